// Round 3
// baseline (135.396 us; speedup 1.0000x reference)
//
#include <hip/hip_runtime.h>

// SSIM fused kernel v3, MI355X (gfx950).
// Changes vs v2 (which was LDS-issue-pipe-bound: 70 ds_read_b32 + 8 ds_write
// per wave, 16 waves/CU saturate the per-CU LDS pipe while VALU sits at 54%):
//  - Row-conv results packed: rbA = half2(conv_p, conv_t), rbB = half2(conv_pp,
//    conv_tt), rbC = f32 conv_pt (kept f32: sigma_xy path has ~150x
//    sensitivity in the SSIM map; mu/sigma_xx paths tolerate fp16 RTN).
//    Stage-2 DS reads: 70 -> 42/thread; stage-1 writes 5 -> 3/item.
//  - LDS 33.8 KB -> 20.0 KB -> 8 blocks/CU (32-wave cap), __launch_bounds__(256,8).

#define HH 512
#define WW 512
#define PLANES 48                 // 16 * 3
#define TW 64
#define TH 16
#define RR 5
#define KK 11
#define IN_H (TH + 2 * RR)        // 26
#define NBLOCKS (PLANES * (WW / TW) * (HH / TH))  // 12288
#define NTHREADS 256
#define NITEMS (IN_H * (TW / 4))  // 416 row-conv items (row, 4-col group)
#define TOTAL_ELEMS (PLANES * HH * WW)            // 12582912

typedef _Float16 half2v __attribute__((ext_vector_type(2)));

__device__ __constant__ float G_[KK] = {
    1.4867195147342977e-06f, 1.3383022576488537e-04f, 4.4318484119380075e-03f,
    5.3990966513188063e-02f, 2.4197072451914337e-01f, 3.9894228040143270e-01f,
    2.4197072451914337e-01f, 5.3990966513188063e-02f, 4.4318484119380075e-03f,
    1.3383022576488537e-04f, 1.4867195147342977e-06f};

__global__ __launch_bounds__(NTHREADS, 8) void ssim_tile_kernel(
    const float* __restrict__ pred, const float* __restrict__ targ,
    float* __restrict__ partial) {
  __shared__ __align__(16) half2v rbA[IN_H][TW];  // (conv p, conv t)
  __shared__ __align__(16) half2v rbB[IN_H][TW];  // (conv pp, conv tt)
  __shared__ __align__(16) float rbC[IN_H][TW];   // conv pt (f32: sensitive)
  __shared__ float wsums[4];

  const int tid = threadIdx.x;
  const int bid = blockIdx.x;
  const int plane = bid >> 8;          // 256 tiles per plane
  const int tile = bid & 255;
  const int x0 = (tile & 7) * TW;
  const int y0 = (tile >> 3) * TH;
  const float* pp = pred + (size_t)plane * (HH * WW);
  const float* tp = targ + (size_t)plane * (HH * WW);

  const bool interior = (x0 >= 64) && (x0 <= 384) && (y0 >= 16) && (y0 <= 480);

  // ---- Stage 1: row convolution of 5 quantities, direct from global ----
  for (int i = tid; i < NITEMS; i += NTHREADS) {
    const int r = i >> 4;              // 0..25 halo row
    const int c4 = (i & 15) << 2;      // 0..60 output col group
    const int gy = y0 + r - RR;

    // window: global cols x0+c4-8 .. x0+c4+11 (20 floats, 16B-aligned start)
    float pw[20], tw[20];
    if (interior) {
      const float* prow = pp + gy * WW + (x0 + c4 - 8);
      const float* trow = tp + gy * WW + (x0 + c4 - 8);
#pragma unroll
      for (int u = 0; u < 5; ++u) {
        float4 a = reinterpret_cast<const float4*>(prow)[u];
        float4 b = reinterpret_cast<const float4*>(trow)[u];
        pw[4 * u + 0] = a.x; pw[4 * u + 1] = a.y;
        pw[4 * u + 2] = a.z; pw[4 * u + 3] = a.w;
        tw[4 * u + 0] = b.x; tw[4 * u + 1] = b.y;
        tw[4 * u + 2] = b.z; tw[4 * u + 3] = b.w;
      }
    } else {
      if (gy >= 0 && gy < HH) {
        const float* prow = pp + gy * WW;
        const float* trow = tp + gy * WW;
#pragma unroll
        for (int j = 3; j <= 16; ++j) {
          int gx = x0 + c4 - 8 + j;
          bool ok = (gx >= 0) && (gx < WW);
          pw[j] = ok ? prow[gx] : 0.f;
          tw[j] = ok ? trow[gx] : 0.f;
        }
      } else {
#pragma unroll
        for (int j = 3; j <= 16; ++j) { pw[j] = 0.f; tw[j] = 0.f; }
      }
    }

    float ppw[14], ttw[14], ptw[14];
#pragma unroll
    for (int j = 0; j < 14; ++j) {
      float a = pw[j + 3], b = tw[j + 3];
      ppw[j] = a * a;
      ttw[j] = b * b;
      ptw[j] = a * b;
    }

    float s[5][4];
#pragma unroll
    for (int q = 0; q < 5; ++q)
#pragma unroll
      for (int j = 0; j < 4; ++j) s[q][j] = 0.f;
#pragma unroll
    for (int j = 0; j < 4; ++j) {
#pragma unroll
      for (int k = 0; k < KK; ++k) {
        const float w = G_[k];
        const int idx = j + k;  // 0..13
        s[0][j] = fmaf(w, pw[idx + 3], s[0][j]);
        s[1][j] = fmaf(w, tw[idx + 3], s[1][j]);
        s[2][j] = fmaf(w, ppw[idx], s[2][j]);
        s[3][j] = fmaf(w, ttw[idx], s[3][j]);
        s[4][j] = fmaf(w, ptw[idx], s[4][j]);
      }
    }
    half2v tA[4], tB[4];
#pragma unroll
    for (int j = 0; j < 4; ++j) {
      tA[j] = half2v{(_Float16)s[0][j], (_Float16)s[1][j]};
      tB[j] = half2v{(_Float16)s[2][j], (_Float16)s[3][j]};
    }
    *reinterpret_cast<float4*>(&rbA[r][c4]) = *reinterpret_cast<float4*>(tA);
    *reinterpret_cast<float4*>(&rbB[r][c4]) = *reinterpret_cast<float4*>(tB);
    *reinterpret_cast<float4*>(&rbC[r][c4]) =
        make_float4(s[4][0], s[4][1], s[4][2], s[4][3]);
  }
  __syncthreads();

  // ---- Stage 2: column convolution + SSIM map (4 vertical outputs/thread) --
  float lsum = 0.f;
  {
    const int x = tid & 63;
    const int ybase = (tid >> 6) * 4;  // 0,4,8,12
    float sA0[4], sA1[4], sB0[4], sB1[4], sC[4];

    {  // group A: mu_x, mu_y
      float va[14], vb[14];
#pragma unroll
      for (int m = 0; m < 14; ++m) {
        half2v h = rbA[ybase + m][x];
        va[m] = (float)h.x;
        vb[m] = (float)h.y;
      }
#pragma unroll
      for (int j = 0; j < 4; ++j) {
        float a0 = 0.f, a1 = 0.f;
#pragma unroll
        for (int k = 0; k < KK; ++k) {
          a0 = fmaf(G_[k], va[j + k], a0);
          a1 = fmaf(G_[k], vb[j + k], a1);
        }
        sA0[j] = a0; sA1[j] = a1;
      }
    }
    {  // group B: E[x^2], E[y^2]
      float va[14], vb[14];
#pragma unroll
      for (int m = 0; m < 14; ++m) {
        half2v h = rbB[ybase + m][x];
        va[m] = (float)h.x;
        vb[m] = (float)h.y;
      }
#pragma unroll
      for (int j = 0; j < 4; ++j) {
        float a0 = 0.f, a1 = 0.f;
#pragma unroll
        for (int k = 0; k < KK; ++k) {
          a0 = fmaf(G_[k], va[j + k], a0);
          a1 = fmaf(G_[k], vb[j + k], a1);
        }
        sB0[j] = a0; sB1[j] = a1;
      }
    }
    {  // group C: E[xy]
      float vc[14];
#pragma unroll
      for (int m = 0; m < 14; ++m) vc[m] = rbC[ybase + m][x];
#pragma unroll
      for (int j = 0; j < 4; ++j) {
        float a = 0.f;
#pragma unroll
        for (int k = 0; k < KK; ++k) a = fmaf(G_[k], vc[j + k], a);
        sC[j] = a;
      }
    }

    const float C1 = 1.0e-4f;  // (0.01*1)^2
    const float C2 = 9.0e-4f;  // (0.03*1)^2
#pragma unroll
    for (int j = 0; j < 4; ++j) {
      float mu_x = sA0[j];
      float mu_y = sA1[j];
      float sxx = sB0[j] - mu_x * mu_x;
      float syy = sB1[j] - mu_y * mu_y;
      float sxy = sC[j] - mu_x * mu_y;
      float num = (2.f * mu_x * mu_y + C1) * (2.f * sxy + C2);
      float den = (mu_x * mu_x + mu_y * mu_y + C1) *
                  (sxx * sxx + syy * syy + C2);
      lsum = fmaf(num, __builtin_amdgcn_rcpf(den), lsum);
    }
  }

  // ---- Block reduction -> partial[bid] ----
#pragma unroll
  for (int off = 32; off > 0; off >>= 1) lsum += __shfl_xor(lsum, off, 64);
  if ((tid & 63) == 0) wsums[tid >> 6] = lsum;
  __syncthreads();
  if (tid == 0)
    partial[bid] = (wsums[0] + wsums[1]) + (wsums[2] + wsums[3]);
}

__global__ __launch_bounds__(1024) void ssim_reduce_kernel(
    const float* __restrict__ partial, float* __restrict__ out) {
  float s = 0.f;
  for (int i = threadIdx.x; i < NBLOCKS; i += 1024) s += partial[i];
#pragma unroll
  for (int off = 32; off > 0; off >>= 1) s += __shfl_xor(s, off, 64);
  __shared__ float ws[16];
  if ((threadIdx.x & 63) == 0) ws[threadIdx.x >> 6] = s;
  __syncthreads();
  if (threadIdx.x == 0) {
    float t = 0.f;
#pragma unroll
    for (int i = 0; i < 16; ++i) t += ws[i];
    out[0] = t * (1.0f / (float)TOTAL_ELEMS);
  }
}

extern "C" void kernel_launch(void* const* d_in, const int* in_sizes, int n_in,
                              void* d_out, int out_size, void* d_ws,
                              size_t ws_size, hipStream_t stream) {
  const float* pred = (const float*)d_in[0];
  const float* targ = (const float*)d_in[1];
  float* out = (float*)d_out;
  float* partial = (float*)d_ws;  // 12288 * 4 = 48 KiB of d_ws

  ssim_tile_kernel<<<NBLOCKS, NTHREADS, 0, stream>>>(pred, targ, partial);
  ssim_reduce_kernel<<<1, 1024, 0, stream>>>(partial, out);
}

// Round 4
// 112.671 us; speedup vs baseline: 1.2017x; 1.2017x over previous
//
#include <hip/hip_runtime.h>

// SSIM fused kernel v4, MI355X (gfx950).
// v3 post-mortem: __launch_bounds__(256,8) (VGPR cap 64) forced VGPR=32 with
// heavy scratch spills (WRITE_SIZE 0.4->176 MB, FETCH 92->135 MB) -> 157 us.
// v4 keeps v3's DS-halving fp16 packing but:
//  - Stage-1 row conv rewritten in SCATTER form: per window position, compute
//    the 5 products once (transient) and accumulate into s[5][4]. Live set
//    ~65-75 VGPR instead of ~100.
//  - __launch_bounds__(256,6): VGPR cap 84 > natural usage -> no spills;
//    6 blocks/CU (24 waves) vs v2's 4.
//  - constexpr Gaussian weights (inline literals, no c-mem loads).

#define HH 512
#define WW 512
#define PLANES 48                 // 16 * 3
#define TW 64
#define TH 16
#define RR 5
#define KK 11
#define IN_H (TH + 2 * RR)        // 26
#define NBLOCKS (PLANES * (WW / TW) * (HH / TH))  // 12288
#define NTHREADS 256
#define NITEMS (IN_H * (TW / 4))  // 416 row-conv items (row, 4-col group)
#define TOTAL_ELEMS (PLANES * HH * WW)            // 12582912

typedef _Float16 half2v __attribute__((ext_vector_type(2)));

constexpr float G_[KK] = {
    1.4867195147342977e-06f, 1.3383022576488537e-04f, 4.4318484119380075e-03f,
    5.3990966513188063e-02f, 2.4197072451914337e-01f, 3.9894228040143270e-01f,
    2.4197072451914337e-01f, 5.3990966513188063e-02f, 4.4318484119380075e-03f,
    1.3383022576488537e-04f, 1.4867195147342977e-06f};

__global__ __launch_bounds__(NTHREADS, 6) void ssim_tile_kernel(
    const float* __restrict__ pred, const float* __restrict__ targ,
    float* __restrict__ partial) {
  __shared__ __align__(16) half2v rbA[IN_H][TW];  // (conv p, conv t)
  __shared__ __align__(16) half2v rbB[IN_H][TW];  // (conv pp, conv tt)
  __shared__ __align__(16) float rbC[IN_H][TW];   // conv pt (f32: sensitive)
  __shared__ float wsums[4];

  const int tid = threadIdx.x;
  const int bid = blockIdx.x;
  const int plane = bid >> 8;          // 256 tiles per plane
  const int tile = bid & 255;
  const int x0 = (tile & 7) * TW;
  const int y0 = (tile >> 3) * TH;
  const float* pp = pred + (size_t)plane * (HH * WW);
  const float* tp = targ + (size_t)plane * (HH * WW);

  const bool interior = (x0 >= 64) && (x0 <= 384) && (y0 >= 16) && (y0 <= 480);

  // ---- Stage 1: row convolution of 5 quantities, direct from global ----
  for (int i = tid; i < NITEMS; i += NTHREADS) {
    const int r = i >> 4;              // 0..25 halo row
    const int c4 = (i & 15) << 2;      // 0..60 output col group
    const int gy = y0 + r - RR;

    // window: global cols x0+c4-8 .. x0+c4+11 (20 floats, 16B-aligned start)
    float4 pf[5], tf[5];
    if (interior) {
      const float* prow = pp + gy * WW + (x0 + c4 - 8);
      const float* trow = tp + gy * WW + (x0 + c4 - 8);
#pragma unroll
      for (int u = 0; u < 5; ++u) {
        pf[u] = reinterpret_cast<const float4*>(prow)[u];
        tf[u] = reinterpret_cast<const float4*>(trow)[u];
      }
    } else {
      float pw[20], tw[20];
      if (gy >= 0 && gy < HH) {
        const float* prow = pp + gy * WW;
        const float* trow = tp + gy * WW;
#pragma unroll
        for (int j = 0; j < 20; ++j) {
          int gx = x0 + c4 - 8 + j;
          bool ok = (j >= 3) && (j <= 16) && (gx >= 0) && (gx < WW);
          pw[j] = ok ? prow[gx] : 0.f;
          tw[j] = ok ? trow[gx] : 0.f;
        }
      } else {
#pragma unroll
        for (int j = 0; j < 20; ++j) { pw[j] = 0.f; tw[j] = 0.f; }
      }
#pragma unroll
      for (int u = 0; u < 5; ++u) {
        pf[u] = make_float4(pw[4*u], pw[4*u+1], pw[4*u+2], pw[4*u+3]);
        tf[u] = make_float4(tw[4*u], tw[4*u+1], tw[4*u+2], tw[4*u+3]);
      }
    }

    // Scatter form: position idx (3..16) contributes to outputs
    // j in [idx-13, idx-3] ∩ [0,3] with weight G_[idx-3-j].
    float s0[4] = {0,0,0,0}, s1[4] = {0,0,0,0}, s2[4] = {0,0,0,0},
          s3[4] = {0,0,0,0}, s4[4] = {0,0,0,0};
#pragma unroll
    for (int u = 0; u < 5; ++u) {
#pragma unroll
      for (int e = 0; e < 4; ++e) {
        const int idx = 4 * u + e;   // window position 0..19
        if (idx < 3 || idx > 16) continue;
        const float a = reinterpret_cast<const float*>(&pf[u])[e];
        const float b = reinterpret_cast<const float*>(&tf[u])[e];
        const float aa = a * a, bb = b * b, ab = a * b;
#pragma unroll
        for (int j = 0; j < 4; ++j) {
          if (j < idx - 13 || j > idx - 3) continue;
          const float w = G_[idx - 3 - j];
          s0[j] = fmaf(w, a, s0[j]);
          s1[j] = fmaf(w, b, s1[j]);
          s2[j] = fmaf(w, aa, s2[j]);
          s3[j] = fmaf(w, bb, s3[j]);
          s4[j] = fmaf(w, ab, s4[j]);
        }
      }
    }

    half2v tA[4], tB[4];
#pragma unroll
    for (int j = 0; j < 4; ++j) {
      tA[j] = half2v{(_Float16)s0[j], (_Float16)s1[j]};
      tB[j] = half2v{(_Float16)s2[j], (_Float16)s3[j]};
    }
    *reinterpret_cast<float4*>(&rbA[r][c4]) = *reinterpret_cast<float4*>(tA);
    *reinterpret_cast<float4*>(&rbB[r][c4]) = *reinterpret_cast<float4*>(tB);
    *reinterpret_cast<float4*>(&rbC[r][c4]) =
        make_float4(s4[0], s4[1], s4[2], s4[3]);
  }
  __syncthreads();

  // ---- Stage 2: column convolution + SSIM map (4 vertical outputs/thread) --
  float lsum = 0.f;
  {
    const int x = tid & 63;
    const int ybase = (tid >> 6) * 4;  // 0,4,8,12
    float sA0[4], sA1[4], sB0[4], sB1[4], sC[4];

    {  // group A: mu_x, mu_y
      float va[14], vb[14];
#pragma unroll
      for (int m = 0; m < 14; ++m) {
        half2v h = rbA[ybase + m][x];
        va[m] = (float)h.x;
        vb[m] = (float)h.y;
      }
#pragma unroll
      for (int j = 0; j < 4; ++j) {
        float a0 = 0.f, a1 = 0.f;
#pragma unroll
        for (int k = 0; k < KK; ++k) {
          a0 = fmaf(G_[k], va[j + k], a0);
          a1 = fmaf(G_[k], vb[j + k], a1);
        }
        sA0[j] = a0; sA1[j] = a1;
      }
    }
    {  // group B: E[x^2], E[y^2]
      float va[14], vb[14];
#pragma unroll
      for (int m = 0; m < 14; ++m) {
        half2v h = rbB[ybase + m][x];
        va[m] = (float)h.x;
        vb[m] = (float)h.y;
      }
#pragma unroll
      for (int j = 0; j < 4; ++j) {
        float a0 = 0.f, a1 = 0.f;
#pragma unroll
        for (int k = 0; k < KK; ++k) {
          a0 = fmaf(G_[k], va[j + k], a0);
          a1 = fmaf(G_[k], vb[j + k], a1);
        }
        sB0[j] = a0; sB1[j] = a1;
      }
    }
    {  // group C: E[xy]
      float vc[14];
#pragma unroll
      for (int m = 0; m < 14; ++m) vc[m] = rbC[ybase + m][x];
#pragma unroll
      for (int j = 0; j < 4; ++j) {
        float a = 0.f;
#pragma unroll
        for (int k = 0; k < KK; ++k) a = fmaf(G_[k], vc[j + k], a);
        sC[j] = a;
      }
    }

    const float C1 = 1.0e-4f;  // (0.01*1)^2
    const float C2 = 9.0e-4f;  // (0.03*1)^2
#pragma unroll
    for (int j = 0; j < 4; ++j) {
      float mu_x = sA0[j];
      float mu_y = sA1[j];
      float sxx = sB0[j] - mu_x * mu_x;
      float syy = sB1[j] - mu_y * mu_y;
      float sxy = sC[j] - mu_x * mu_y;
      float num = (2.f * mu_x * mu_y + C1) * (2.f * sxy + C2);
      float den = (mu_x * mu_x + mu_y * mu_y + C1) *
                  (sxx * sxx + syy * syy + C2);
      lsum = fmaf(num, __builtin_amdgcn_rcpf(den), lsum);
    }
  }

  // ---- Block reduction -> partial[bid] ----
#pragma unroll
  for (int off = 32; off > 0; off >>= 1) lsum += __shfl_xor(lsum, off, 64);
  if ((tid & 63) == 0) wsums[tid >> 6] = lsum;
  __syncthreads();
  if (tid == 0)
    partial[bid] = (wsums[0] + wsums[1]) + (wsums[2] + wsums[3]);
}

__global__ __launch_bounds__(1024) void ssim_reduce_kernel(
    const float* __restrict__ partial, float* __restrict__ out) {
  float s = 0.f;
  for (int i = threadIdx.x; i < NBLOCKS; i += 1024) s += partial[i];
#pragma unroll
  for (int off = 32; off > 0; off >>= 1) s += __shfl_xor(s, off, 64);
  __shared__ float ws[16];
  if ((threadIdx.x & 63) == 0) ws[threadIdx.x >> 6] = s;
  __syncthreads();
  if (threadIdx.x == 0) {
    float t = 0.f;
#pragma unroll
    for (int i = 0; i < 16; ++i) t += ws[i];
    out[0] = t * (1.0f / (float)TOTAL_ELEMS);
  }
}

extern "C" void kernel_launch(void* const* d_in, const int* in_sizes, int n_in,
                              void* d_out, int out_size, void* d_ws,
                              size_t ws_size, hipStream_t stream) {
  const float* pred = (const float*)d_in[0];
  const float* targ = (const float*)d_in[1];
  float* out = (float*)d_out;
  float* partial = (float*)d_ws;  // 12288 * 4 = 48 KiB of d_ws

  ssim_tile_kernel<<<NBLOCKS, NTHREADS, 0, stream>>>(pred, targ, partial);
  ssim_reduce_kernel<<<1, 1024, 0, stream>>>(partial, out);
}

// Round 8
// 86.364 us; speedup vs baseline: 1.5677x; 1.3046x over previous
//
#include <hip/hip_runtime.h>
#include <stdint.h>

// SSIM fused kernel v8, MI355X (gfx950).
// v7 post-mortem: cvt_pkrtz = round-toward-ZERO storage biased mu by -1.2e-4,
// which shows up as +2.4e-4 bias in 2*sigma_xy; with sigma_xy ~ 0 and
// C2 = 9e-4 that's ~27% bias in the structure numerator -> mean off by 2.9e-2.
// v4 proved RTN fp16 storage is exact-enough (absmax 0.0). v8 = v7 with RTN
// ((_Float16) casts) instead of cvt_pkrtz. Everything else unchanged:
//  - Stage 0: LDS staging of raw 80x26 halo (aligned float4, uniform path).
//  - Stage 1: row conv of 5 quantities, packed f32 (v_pk_fma_f32) for the
//    (p,t) and (pp,tt) pairs; pt scalar f32.
//  - rbAB: fp16-packed (RTN) storage of f32-accumulated row-conv results;
//    rbC f32. LDS 36.6 KB -> 4 blocks/CU.
//  - Stage 2: column conv packed f32 + SSIM map + 2-kernel mean reduction.

#define HH 512
#define WW 512
#define PLANES 48
#define TW 64
#define TH 16
#define RR 5
#define KK 11
#define IN_H (TH + 2 * RR)        // 26
#define SW 80                      // staged cols: x0-8 .. x0+71
#define NBLOCKS (PLANES * (WW / TW) * (HH / TH))  // 12288
#define NTHREADS 256
#define NITEMS (IN_H * (TW / 4))  // 416
#define NSTAGE (IN_H * (SW / 4))  // 520 staging granules
#define TOTAL_ELEMS (PLANES * HH * WW)

typedef _Float16 half2v __attribute__((ext_vector_type(2)));
typedef float float2v __attribute__((ext_vector_type(2)));

constexpr float G_[KK] = {
    1.4867195147342977e-06f, 1.3383022576488537e-04f, 4.4318484119380075e-03f,
    5.3990966513188063e-02f, 2.4197072451914337e-01f, 3.9894228040143270e-01f,
    2.4197072451914337e-01f, 5.3990966513188063e-02f, 4.4318484119380075e-03f,
    1.3383022576488537e-04f, 1.4867195147342977e-06f};

__device__ __forceinline__ half2v u2h(uint32_t u) {
  return __builtin_bit_cast(half2v, u);
}
// RTN fp16 pack (v_cvt_f16_f32 x2 + pack) — unbiased, verified by v4.
__device__ __forceinline__ uint32_t packrtn(float a, float b) {
  half2v h = {(_Float16)a, (_Float16)b};
  return __builtin_bit_cast(uint32_t, h);
}

__global__ __launch_bounds__(NTHREADS, 4) void ssim_tile_kernel(
    const float* __restrict__ pred, const float* __restrict__ targ,
    float* __restrict__ partial) {
  __shared__ __align__(16) float sp[IN_H][SW];    // 8.3 KB raw pred
  __shared__ __align__(16) float st[IN_H][SW];    // 8.3 KB raw targ
  __shared__ __align__(16) uint2 rbAB[IN_H][TW];  // 13.3 KB {pack(p,t),pack(pp,tt)}
  __shared__ __align__(16) float rbC[IN_H][TW];   // 6.7 KB conv_pt f32
  __shared__ float wsums[4];

  const int tid = threadIdx.x;
  const int bid = blockIdx.x;
  const int plane = bid >> 8;
  const int tile = bid & 255;
  const int x0 = (tile & 7) * TW;
  const int y0 = (tile >> 3) * TH;
  const float* pp = pred + (size_t)plane * (HH * WW);
  const float* tp = targ + (size_t)plane * (HH * WW);

  // ---- Stage 0: stage raw halo (granule-aligned float4, uniform path) ----
  for (int i = tid; i < NSTAGE; i += NTHREADS) {
    const int r = i / 20;            // halo row 0..25
    const int cg = i - r * 20;       // granule 0..19
    const int gy = y0 + r - RR;
    const int gx = x0 - 8 + cg * 4;  // granule start, 16B aligned
    float4 pv = make_float4(0.f, 0.f, 0.f, 0.f);
    float4 tv = pv;
    if (gy >= 0 && gy < HH && gx >= 0 && gx <= WW - 4) {
      const int o = gy * WW + gx;
      pv = *reinterpret_cast<const float4*>(pp + o);
      tv = *reinterpret_cast<const float4*>(tp + o);
    }
    *reinterpret_cast<float4*>(&sp[r][cg * 4]) = pv;
    *reinterpret_cast<float4*>(&st[r][cg * 4]) = tv;
  }
  __syncthreads();

  // ---- Stage 1: row conv of 5 quantities, packed f32 math ----
  for (int i = tid; i < NITEMS; i += NTHREADS) {
    const int r = i >> 4;            // 0..25
    const int c4 = (i & 15) << 2;    // 0..60
    // staged window cols c4 .. c4+19 (global x0+c4-8 .. x0+c4+11)
    float pw[20], tw[20];
#pragma unroll
    for (int u = 0; u < 5; ++u) {
      float4 a = *reinterpret_cast<const float4*>(&sp[r][c4 + 4 * u]);
      float4 b = *reinterpret_cast<const float4*>(&st[r][c4 + 4 * u]);
      pw[4*u+0] = a.x; pw[4*u+1] = a.y; pw[4*u+2] = a.z; pw[4*u+3] = a.w;
      tw[4*u+0] = b.x; tw[4*u+1] = b.y; tw[4*u+2] = b.z; tw[4*u+3] = b.w;
    }

    float2v s01[4] = {{0,0},{0,0},{0,0},{0,0}};
    float2v s23[4] = {{0,0},{0,0},{0,0},{0,0}};
    float s4[4] = {0,0,0,0};
#pragma unroll
    for (int idx = 3; idx <= 16; ++idx) {
      const float a = pw[idx];
      const float b = tw[idx];
      const float2v av = {a, b};
      const float2v sq = av * av;      // v_pk_mul_f32
      const float ab = a * b;
#pragma unroll
      for (int j = 0; j < 4; ++j) {
        if (j < idx - 13 || j > idx - 3) continue;
        const float w = G_[idx - 3 - j];
        const float2v w2 = {w, w};
        s01[j] = __builtin_elementwise_fma(w2, av, s01[j]);  // v_pk_fma_f32
        s23[j] = __builtin_elementwise_fma(w2, sq, s23[j]);
        s4[j] = fmaf(w, ab, s4[j]);
      }
    }

    uint4 w1, w2s;
    w1.x = packrtn(s01[0].x, s01[0].y); w1.y = packrtn(s23[0].x, s23[0].y);
    w1.z = packrtn(s01[1].x, s01[1].y); w1.w = packrtn(s23[1].x, s23[1].y);
    w2s.x = packrtn(s01[2].x, s01[2].y); w2s.y = packrtn(s23[2].x, s23[2].y);
    w2s.z = packrtn(s01[3].x, s01[3].y); w2s.w = packrtn(s23[3].x, s23[3].y);
    *reinterpret_cast<uint4*>(&rbAB[r][c4]) = w1;
    *reinterpret_cast<uint4*>(&rbAB[r][c4 + 2]) = w2s;
    *reinterpret_cast<float4*>(&rbC[r][c4]) =
        make_float4(s4[0], s4[1], s4[2], s4[3]);
  }
  __syncthreads();

  // ---- Stage 2: column conv (packed f32) + SSIM map ----
  float lsum = 0.f;
  {
    const int x = tid & 63;
    const int ybase = (tid >> 6) * 4;  // 0,4,8,12
    // read packed rows once, unpack to f32 pairs
    float2v fa[14], fb[14];
    float vc[14];
#pragma unroll
    for (int m = 0; m < 14; ++m) {
      uint2 q = rbAB[ybase + m][x];    // ds_read_b64
      half2v ha = u2h(q.x), hb = u2h(q.y);
      fa[m] = float2v{(float)ha.x, (float)ha.y};
      fb[m] = float2v{(float)hb.x, (float)hb.y};
      vc[m] = rbC[ybase + m][x];
    }

    float2v accA[4], accB[4];
    float sC[4];
#pragma unroll
    for (int j = 0; j < 4; ++j) {
      float2v a = {0, 0}, b = {0, 0};
      float c = 0.f;
#pragma unroll
      for (int k = 0; k < KK; ++k) {
        const float2v w2 = {G_[k], G_[k]};
        a = __builtin_elementwise_fma(w2, fa[j + k], a);
        b = __builtin_elementwise_fma(w2, fb[j + k], b);
        c = fmaf(G_[k], vc[j + k], c);
      }
      accA[j] = a; accB[j] = b; sC[j] = c;
    }

    const float C1 = 1.0e-4f;
    const float C2 = 9.0e-4f;
#pragma unroll
    for (int j = 0; j < 4; ++j) {
      float mu_x = accA[j].x;
      float mu_y = accA[j].y;
      float sxx = accB[j].x - mu_x * mu_x;
      float syy = accB[j].y - mu_y * mu_y;
      float sxy = sC[j] - mu_x * mu_y;
      float num = (2.f * mu_x * mu_y + C1) * (2.f * sxy + C2);
      float den = (mu_x * mu_x + mu_y * mu_y + C1) *
                  (sxx * sxx + syy * syy + C2);
      lsum = fmaf(num, __builtin_amdgcn_rcpf(den), lsum);
    }
  }

  // ---- Block reduction -> partial[bid] ----
#pragma unroll
  for (int off = 32; off > 0; off >>= 1) lsum += __shfl_xor(lsum, off, 64);
  if ((tid & 63) == 0) wsums[tid >> 6] = lsum;
  __syncthreads();
  if (tid == 0)
    partial[bid] = (wsums[0] + wsums[1]) + (wsums[2] + wsums[3]);
}

__global__ __launch_bounds__(1024) void ssim_reduce_kernel(
    const float* __restrict__ partial, float* __restrict__ out) {
  float s = 0.f;
  for (int i = threadIdx.x; i < NBLOCKS; i += 1024) s += partial[i];
#pragma unroll
  for (int off = 32; off > 0; off >>= 1) s += __shfl_xor(s, off, 64);
  __shared__ float ws[16];
  if ((threadIdx.x & 63) == 0) ws[threadIdx.x >> 6] = s;
  __syncthreads();
  if (threadIdx.x == 0) {
    float t = 0.f;
#pragma unroll
    for (int i = 0; i < 16; ++i) t += ws[i];
    out[0] = t * (1.0f / (float)TOTAL_ELEMS);
  }
}

extern "C" void kernel_launch(void* const* d_in, const int* in_sizes, int n_in,
                              void* d_out, int out_size, void* d_ws,
                              size_t ws_size, hipStream_t stream) {
  const float* pred = (const float*)d_in[0];
  const float* targ = (const float*)d_in[1];
  float* out = (float*)d_out;
  float* partial = (float*)d_ws;

  ssim_tile_kernel<<<NBLOCKS, NTHREADS, 0, stream>>>(pred, targ, partial);
  ssim_reduce_kernel<<<1, 1024, 0, stream>>>(partial, out);
}